// Round 4
// baseline (305.315 us; speedup 1.0000x reference)
//
#include <hip/hip_runtime.h>
#include <hip/hip_fp16.h>

// Per-point expert-indexed MLP: h = LeakyReLU(h @ W[idx] + b[idx]) x3.
//
// R14: single fused kernel + BLOCK-LOCAL SORT + 2-point interleave.
// R13 post-mortem: 55us with VALUBusy 17%, LDS conflicts 0, occupancy 26% ->
// latency-bound; 64 lanes reading up to 16 DISTINCT expert granules per
// ds_read_b128 puts ~22us of unique-address traffic on the LDS pipe at ~40%
// utilization. Fix: sort the block's 512 points by expert in LDS (hist +
// 16-lane scan + rank scatter, packed (e<<9)|local ushort). Sorted waves span
// ~2 experts -> weight ds_reads are ~wave-uniform -> broadcast (free, m136)
// -> LDS unique traffic /6. Interleave the thread's 2 points for dual
// independent dep-chains (ILP vs ds_read latency). Fences between layers
// contain VGPR (<=128 under launch_bounds(256,4)).
// LDS 40576 B <= 40960 -> still 4 blocks/CU.
//
// L0 bias folded into the c=7 pad slot (x7 = 1.0, w7 = b0[o]). b2 as fp16
// (keeps LDS under the 4-block boundary; error ~5e-4 << fp16-weight error).

#define L_EXP 16
#define IN0   7
#define C0    16
#define C1    32
#define C2    16
#define NEG   0.2f
#define BLK   256
#define PPB   512         // points per block (2 per thread)

typedef _Float16 h2 __attribute__((ext_vector_type(2)));
union F4H { float4 f4; h2 h[4]; };

__device__ __forceinline__ h2 pk(float a, float b) {
    return __builtin_bit_cast(h2, __builtin_amdgcn_cvt_pkrtz(a, b));
}
__device__ __forceinline__ float leaky(float a) { return fmaxf(a, NEG * a); }
__device__ __forceinline__ float fdot2(h2 a, h2 b, float c) {
    return __builtin_amdgcn_fdot2(a, b, c, false);
}

__global__ void __launch_bounds__(BLK, 4) k_fused(
    const float* __restrict__ x, const int* __restrict__ idx,
    const float* __restrict__ W0, const float* __restrict__ b0,
    const float* __restrict__ W1, const float* __restrict__ b1,
    const float* __restrict__ W2, const float* __restrict__ b2,
    float* __restrict__ out, int n) {
    // expert-innermost fp16 weight tiles; 16 B per (row, expert)
    __shared__ __align__(16) __half sW0[C0 * L_EXP * 8];      // [o][e][8]  4 KB
    __shared__ __align__(16) __half sW1[C1 * 2 * L_EXP * 8];  // [o][q][e][8] 16 KB
    __shared__ __align__(16) __half sW2[C2 * 4 * L_EXP * 8];  // [o][q][e][8] 16 KB
    __shared__ float  sB1[C1 * L_EXP];                        // [o][e] 2 KB
    __shared__ __half sB2h[C2 * L_EXP];                       // [o][e] 512 B
    __shared__ unsigned short spid[PPB];                      // sorted (e<<9)|local, 1 KB
    __shared__ int bins[L_EXP];                               // 64 B
    __shared__ int poff[L_EXP];                               // 64 B

    int t = threadIdx.x;

    // ---- stage all experts' weights (once per block) ----
    {   // W0: 256 rows of 8 halves; row k: o=k>>4, e=k&15; c=0..6 + bias slot
        int o = t >> 4, e = t & 15;
        float v0 = W0[e * (IN0 * C0) + 0 * C0 + o];
        float v1 = W0[e * (IN0 * C0) + 1 * C0 + o];
        float v2 = W0[e * (IN0 * C0) + 2 * C0 + o];
        float v3 = W0[e * (IN0 * C0) + 3 * C0 + o];
        float v4 = W0[e * (IN0 * C0) + 4 * C0 + o];
        float v5 = W0[e * (IN0 * C0) + 5 * C0 + o];
        float v6 = W0[e * (IN0 * C0) + 6 * C0 + o];
        float v7 = b0[e * C0 + o];           // bias via x7=1.0
        F4H u;
        u.h[0] = pk(v0, v1); u.h[1] = pk(v2, v3);
        u.h[2] = pk(v4, v5); u.h[3] = pk(v6, v7);
        reinterpret_cast<float4*>(sW0)[t] = u.f4;
    }
#pragma unroll
    for (int rr = 0; rr < 4; ++rr) {  // W1: 1024 rows; row r=(o*2+q)*16+e
        int r = rr * BLK + t;
        int o = r >> 5, q = (r >> 4) & 1, e = r & 15;
        const float* wp = W1 + e * (C0 * C1) + (q * 8) * C1 + o;
        F4H u;
#pragma unroll
        for (int j = 0; j < 4; ++j)
            u.h[j] = pk(wp[(2 * j) * C1], wp[(2 * j + 1) * C1]);
        reinterpret_cast<float4*>(sW1)[r] = u.f4;
    }
#pragma unroll
    for (int rr = 0; rr < 4; ++rr) {  // W2: 1024 rows; row r=(o*4+q)*16+e
        int r = rr * BLK + t;
        int o = r >> 6, q = (r >> 4) & 3, e = r & 15;
        const float* wp = W2 + e * (C1 * C2) + (q * 8) * C2 + o;
        F4H u;
#pragma unroll
        for (int j = 0; j < 4; ++j)
            u.h[j] = pk(wp[(2 * j) * C2], wp[(2 * j + 1) * C2]);
        reinterpret_cast<float4*>(sW2)[r] = u.f4;
    }
    {   // biases [o][e]
        int o = t >> 4, e = t & 15;
        sB1[t] = b1[e * C1 + o];                       // o 0..15
        int r2 = t + 256; int o2 = r2 >> 4, e2 = r2 & 15;
        sB1[r2] = b1[e2 * C1 + o2];                    // o 16..31
        sB2h[t] = __float2half(b2[e * C2 + o]);
    }
    if (t < L_EXP) bins[t] = 0;
    __syncthreads();

    // ---- block-local expert sort of 512 points ----
    int base = blockIdx.x * PPB;
    int cnt = n - base; if (cnt > PPB) cnt = PPB;
    int e0 = 0, r0 = 0, e1 = 0, r1 = 0;
    bool v0 = (t < cnt), v1 = (t + 256 < cnt);
    if (v0) { e0 = idx[base + t] & 15;       r0 = atomicAdd(&bins[e0], 1); }
    if (v1) { e1 = idx[base + t + 256] & 15; r1 = atomicAdd(&bins[e1], 1); }
    __syncthreads();
    if (t < L_EXP) {   // 16-lane exclusive scan (lanes 0..15 of wave 0)
        int c = bins[t], s = c;
#pragma unroll
        for (int d = 1; d < L_EXP; d <<= 1) {
            int u = __shfl_up(s, d, L_EXP);
            if (t >= d) s += u;
        }
        poff[t] = s - c;
    }
    __syncthreads();
    if (v0) spid[poff[e0] + r0] = (unsigned short)((e0 << 9) | t);
    if (v1) spid[poff[e1] + r1] = (unsigned short)((e1 << 9) | (t + 256));
    __syncthreads();

    // ---- process slots t (P) and t+256 (Q), interleaved ----
    bool act0 = (t < cnt), act1 = (t + 256 < cnt);
    int sp0 = act0 ? (int)spid[t] : 0;
    int sp1 = act1 ? (int)spid[t + 256] : 0;
    int eP = sp0 >> 9, pidP = base + (sp0 & 511);
    int eQ = sp1 >> 9, pidQ = base + (sp1 & 511);

    const float* xpP = x + (size_t)pidP * IN0;
    const float* xpQ = x + (size_t)pidQ * IN0;
    float4 aP = *reinterpret_cast<const float4*>(xpP);
    float4 bP = *reinterpret_cast<const float4*>(xpP + 3);
    float4 aQ = *reinterpret_cast<const float4*>(xpQ);
    float4 bQ = *reinterpret_cast<const float4*>(xpQ + 3);
    h2 xP0 = pk(aP.x, aP.y), xP1 = pk(aP.z, aP.w);
    h2 xP2 = pk(bP.y, bP.z), xP3 = pk(bP.w, 1.0f);   // 1.0 -> bias slot
    h2 xQ0 = pk(aQ.x, aQ.y), xQ1 = pk(aQ.z, aQ.w);
    h2 xQ2 = pk(bQ.y, bQ.z), xQ3 = pk(bQ.w, 1.0f);

    const char* w0P = (const char*)sW0 + eP * 16;
    const char* w1P = (const char*)sW1 + eP * 16;
    const char* w2P = (const char*)sW2 + eP * 16;
    const char* w0Q = (const char*)sW0 + eQ * 16;
    const char* w1Q = (const char*)sW1 + eQ * 16;
    const char* w2Q = (const char*)sW2 + eQ * 16;

    // ---- Layer 0: 7(+bias) -> 16 ----
    h2 hP[8], hQ[8];
#pragma unroll
    for (int op = 0; op < 8; ++op) {
        F4H uaP, ubP, uaQ, ubQ;
        uaP.f4 = *reinterpret_cast<const float4*>(w0P + (2 * op) * 256);
        ubP.f4 = *reinterpret_cast<const float4*>(w0P + (2 * op + 1) * 256);
        uaQ.f4 = *reinterpret_cast<const float4*>(w0Q + (2 * op) * 256);
        ubQ.f4 = *reinterpret_cast<const float4*>(w0Q + (2 * op + 1) * 256);
        float p0 = 0.f, p1 = 0.f, q0 = 0.f, q1 = 0.f;
        p0 = fdot2(xP0, uaP.h[0], p0); p1 = fdot2(xP0, ubP.h[0], p1);
        q0 = fdot2(xQ0, uaQ.h[0], q0); q1 = fdot2(xQ0, ubQ.h[0], q1);
        p0 = fdot2(xP1, uaP.h[1], p0); p1 = fdot2(xP1, ubP.h[1], p1);
        q0 = fdot2(xQ1, uaQ.h[1], q0); q1 = fdot2(xQ1, ubQ.h[1], q1);
        p0 = fdot2(xP2, uaP.h[2], p0); p1 = fdot2(xP2, ubP.h[2], p1);
        q0 = fdot2(xQ2, uaQ.h[2], q0); q1 = fdot2(xQ2, ubQ.h[2], q1);
        p0 = fdot2(xP3, uaP.h[3], p0); p1 = fdot2(xP3, ubP.h[3], p1);
        q0 = fdot2(xQ3, uaQ.h[3], q0); q1 = fdot2(xQ3, ubQ.h[3], q1);
        hP[op] = pk(leaky(p0), leaky(p1));
        hQ[op] = pk(leaky(q0), leaky(q1));
    }
    __builtin_amdgcn_sched_barrier(0);

    // ---- Layer 1: 16 -> 32 ----
    h2 tP[16], tQ[16];
#pragma unroll
    for (int op = 0; op < 16; ++op) {
        F4H uaP, ubP, ucP, udP, uaQ, ubQ, ucQ, udQ;
        uaP.f4 = *reinterpret_cast<const float4*>(w1P + (4 * op + 0) * 256);
        ubP.f4 = *reinterpret_cast<const float4*>(w1P + (4 * op + 1) * 256);
        ucP.f4 = *reinterpret_cast<const float4*>(w1P + (4 * op + 2) * 256);
        udP.f4 = *reinterpret_cast<const float4*>(w1P + (4 * op + 3) * 256);
        uaQ.f4 = *reinterpret_cast<const float4*>(w1Q + (4 * op + 0) * 256);
        ubQ.f4 = *reinterpret_cast<const float4*>(w1Q + (4 * op + 1) * 256);
        ucQ.f4 = *reinterpret_cast<const float4*>(w1Q + (4 * op + 2) * 256);
        udQ.f4 = *reinterpret_cast<const float4*>(w1Q + (4 * op + 3) * 256);
        float p0 = sB1[(2 * op) * 16 + eP];
        float p1 = sB1[(2 * op + 1) * 16 + eP];
        float q0 = sB1[(2 * op) * 16 + eQ];
        float q1 = sB1[(2 * op + 1) * 16 + eQ];
#pragma unroll
        for (int p = 0; p < 4; ++p) {
            p0 = fdot2(hP[p], uaP.h[p], p0);
            p1 = fdot2(hP[p], ucP.h[p], p1);
            q0 = fdot2(hQ[p], uaQ.h[p], q0);
            q1 = fdot2(hQ[p], ucQ.h[p], q1);
        }
#pragma unroll
        for (int p = 0; p < 4; ++p) {
            p0 = fdot2(hP[4 + p], ubP.h[p], p0);
            p1 = fdot2(hP[4 + p], udP.h[p], p1);
            q0 = fdot2(hQ[4 + p], ubQ.h[p], q0);
            q1 = fdot2(hQ[4 + p], udQ.h[p], q1);
        }
        tP[op] = pk(leaky(p0), leaky(p1));
        tQ[op] = pk(leaky(q0), leaky(q1));
    }
    __builtin_amdgcn_sched_barrier(0);

    // ---- Layer 2: 32 -> 16, store per output-quad to cap liveness ----
    float4* outP = reinterpret_cast<float4*>(out + (size_t)pidP * C2);
    float4* outQ = reinterpret_cast<float4*>(out + (size_t)pidQ * C2);
#pragma unroll
    for (int og = 0; og < 4; ++og) {
        float4 oP, oQ;
#pragma unroll
        for (int j = 0; j < 4; ++j) {
            int o = og * 4 + j;
            F4H uaP, ubP, ucP, udP, uaQ, ubQ, ucQ, udQ;
            uaP.f4 = *reinterpret_cast<const float4*>(w2P + (4 * o + 0) * 256);
            ubP.f4 = *reinterpret_cast<const float4*>(w2P + (4 * o + 1) * 256);
            ucP.f4 = *reinterpret_cast<const float4*>(w2P + (4 * o + 2) * 256);
            udP.f4 = *reinterpret_cast<const float4*>(w2P + (4 * o + 3) * 256);
            uaQ.f4 = *reinterpret_cast<const float4*>(w2Q + (4 * o + 0) * 256);
            ubQ.f4 = *reinterpret_cast<const float4*>(w2Q + (4 * o + 1) * 256);
            ucQ.f4 = *reinterpret_cast<const float4*>(w2Q + (4 * o + 2) * 256);
            udQ.f4 = *reinterpret_cast<const float4*>(w2Q + (4 * o + 3) * 256);
            float ap = __half2float(sB2h[o * 16 + eP]);
            float aq = __half2float(sB2h[o * 16 + eQ]);
#pragma unroll
            for (int p = 0; p < 4; ++p) ap = fdot2(tP[p],      uaP.h[p], ap);
#pragma unroll
            for (int p = 0; p < 4; ++p) ap = fdot2(tP[4 + p],  ubP.h[p], ap);
#pragma unroll
            for (int p = 0; p < 4; ++p) ap = fdot2(tP[8 + p],  ucP.h[p], ap);
#pragma unroll
            for (int p = 0; p < 4; ++p) ap = fdot2(tP[12 + p], udP.h[p], ap);
#pragma unroll
            for (int p = 0; p < 4; ++p) aq = fdot2(tQ[p],      uaQ.h[p], aq);
#pragma unroll
            for (int p = 0; p < 4; ++p) aq = fdot2(tQ[4 + p],  ubQ.h[p], aq);
#pragma unroll
            for (int p = 0; p < 4; ++p) aq = fdot2(tQ[8 + p],  ucQ.h[p], aq);
#pragma unroll
            for (int p = 0; p < 4; ++p) aq = fdot2(tQ[12 + p], udQ.h[p], aq);
            float rp = leaky(ap), rq = leaky(aq);
            if (j == 0) { oP.x = rp; oQ.x = rq; }
            else if (j == 1) { oP.y = rp; oQ.y = rq; }
            else if (j == 2) { oP.z = rp; oQ.z = rq; }
            else { oP.w = rp; oQ.w = rq; }
        }
        if (act0) outP[og] = oP;
        if (act1) outQ[og] = oQ;
    }
}

extern "C" void kernel_launch(void* const* d_in, const int* in_sizes, int n_in,
                              void* d_out, int out_size, void* d_ws, size_t ws_size,
                              hipStream_t stream) {
    const float* x  = (const float*)d_in[0];
    const int*  idx = (const int*)d_in[1];
    const float* W0 = (const float*)d_in[2];
    const float* b0 = (const float*)d_in[3];
    const float* W1 = (const float*)d_in[4];
    const float* b1 = (const float*)d_in[5];
    const float* W2 = (const float*)d_in[6];
    const float* b2 = (const float*)d_in[7];
    float* out = (float*)d_out;

    int n = in_sizes[1];  // N
    int blocks = (n + PPB - 1) / PPB;
    k_fused<<<blocks, BLK, 0, stream>>>(x, idx, W0, b0, W1, b1, W2, b2, out, n);
}

// Round 5
// 123.050 us; speedup vs baseline: 2.4812x; 2.4812x over previous
//
#include <hip/hip_runtime.h>
#include <hip/hip_fp16.h>

// Per-point expert-indexed MLP: h = LeakyReLU(h @ W[idx] + b[idx]) x3.
//
// R15: single kernel = R13 all-expert LDS weights + block-local sort with
// PAD-TO-4 expert groups + R1-style MPT=4 weight-amortized MLP body.
//
// R14 post-mortem: dual-point full interleave at launch_bounds(256,4) spilled
// (WRITE_SIZE 395 MB of scratch, 240us). Fix: thread processes 4 CONSECUTIVE
// sorted slots (same expert, guaranteed by 4-aligned expert groups) so each
// weight ds_read_b128 serves 4 points: 36 b128/pt (was 144). Sequential
// pairwise L0, #pragma unroll 1 ch-loop for fused L1+L2 (R1's proven
// spill containment), launch_bounds(256,2) -> 256 VGPR cap.
//
// Model: LDS 144 b128/thread/4pts -> ~5.5us; VALU 576 fdot2/pt + pack ~5us;
// HBM 48 MB coalesced-ish ~8us. Expect kernel ~15-22us.
// PPB=976 so padded slot count <= 976+16*3 = 1024 = 256 thr x 4 slots.
// L0 bias folded into c=7 pad slot (x7=1.0, w7=b0[o]); b2 staged fp16.

#define L_EXP 16
#define IN0   7
#define C0    16
#define C1    32
#define C2    16
#define NEG   0.2f
#define BLK   256
#define PPB   976         // points per block (padded slots <= 1024)

typedef _Float16 h2 __attribute__((ext_vector_type(2)));
union F4H { float4 f4; h2 h[4]; };

__device__ __forceinline__ h2 pk(float a, float b) {
    return __builtin_bit_cast(h2, __builtin_amdgcn_cvt_pkrtz(a, b));
}
__device__ __forceinline__ float leaky(float a) { return fmaxf(a, NEG * a); }
__device__ __forceinline__ float fdot2(h2 a, h2 b, float c) {
    return __builtin_amdgcn_fdot2(a, b, c, false);
}

__global__ void __launch_bounds__(BLK, 2) k_fused(
    const float* __restrict__ x, const int* __restrict__ idx,
    const float* __restrict__ W0, const float* __restrict__ b0,
    const float* __restrict__ W1, const float* __restrict__ b1,
    const float* __restrict__ W2, const float* __restrict__ b2,
    float* __restrict__ out, int n) {
    // expert-innermost fp16 weight tiles; 16 B per (row, expert)
    __shared__ __align__(16) __half sW0[C0 * L_EXP * 8];      // [o][e][8]  4 KB
    __shared__ __align__(16) __half sW1[C1 * 2 * L_EXP * 8];  // [o][q2][e][8] 16 KB
    __shared__ __align__(16) __half sW2[C2 * 4 * L_EXP * 8];  // [o][q4][e][8] 16 KB
    __shared__ float  sB1[C1 * L_EXP];                        // [o][e] 2 KB
    __shared__ __half sB2h[C2 * L_EXP];                       // [o][e] 512 B
    __shared__ unsigned short spid[1024];                     // (e<<10)|local, 2 KB
    __shared__ int bins[L_EXP];
    __shared__ int poff[L_EXP];

    int t = threadIdx.x;

    // ---- stage all experts' weights (once per block; proven R13 code) ----
    {   // W0: 256 rows of 8 halves; row k: o=k>>4, e=k&15; c=0..6 + bias slot
        int o = t >> 4, e = t & 15;
        float v0 = W0[e * (IN0 * C0) + 0 * C0 + o];
        float v1 = W0[e * (IN0 * C0) + 1 * C0 + o];
        float v2 = W0[e * (IN0 * C0) + 2 * C0 + o];
        float v3 = W0[e * (IN0 * C0) + 3 * C0 + o];
        float v4 = W0[e * (IN0 * C0) + 4 * C0 + o];
        float v5 = W0[e * (IN0 * C0) + 5 * C0 + o];
        float v6 = W0[e * (IN0 * C0) + 6 * C0 + o];
        float v7 = b0[e * C0 + o];           // bias via x7=1.0
        F4H u;
        u.h[0] = pk(v0, v1); u.h[1] = pk(v2, v3);
        u.h[2] = pk(v4, v5); u.h[3] = pk(v6, v7);
        reinterpret_cast<float4*>(sW0)[t] = u.f4;
    }
#pragma unroll
    for (int rr = 0; rr < 4; ++rr) {  // W1: 1024 rows; row r=(o*2+q2)*16+e
        int r = rr * BLK + t;
        int o = r >> 5, q = (r >> 4) & 1, e = r & 15;
        const float* wp = W1 + e * (C0 * C1) + (q * 8) * C1 + o;
        F4H u;
#pragma unroll
        for (int j = 0; j < 4; ++j)
            u.h[j] = pk(wp[(2 * j) * C1], wp[(2 * j + 1) * C1]);
        reinterpret_cast<float4*>(sW1)[r] = u.f4;
    }
#pragma unroll
    for (int rr = 0; rr < 4; ++rr) {  // W2: 1024 rows; row r=(o*4+q4)*16+e
        int r = rr * BLK + t;
        int o = r >> 6, q = (r >> 4) & 3, e = r & 15;
        const float* wp = W2 + e * (C1 * C2) + (q * 8) * C2 + o;
        F4H u;
#pragma unroll
        for (int j = 0; j < 4; ++j)
            u.h[j] = pk(wp[(2 * j) * C2], wp[(2 * j + 1) * C2]);
        reinterpret_cast<float4*>(sW2)[r] = u.f4;
    }
    {   // biases [o][e]
        int o = t >> 4, e = t & 15;
        sB1[t] = b1[e * C1 + o];                       // o 0..15
        int r2 = t + 256; int o2 = r2 >> 4, e2 = r2 & 15;
        sB1[r2] = b1[e2 * C1 + o2];                    // o 16..31
        sB2h[t] = __float2half(b2[e * C2 + o]);
    }
    if (t < L_EXP) bins[t] = 0;
    {   // init slot array to invalid
        reinterpret_cast<int*>(spid)[t] = -1;
        reinterpret_cast<int*>(spid)[t + 256] = -1;
    }
    __syncthreads();

    // ---- block-local sort of up to 976 points, expert groups padded to 4 ----
    int base = blockIdx.x * PPB;
    int cnt = n - base; if (cnt > PPB) cnt = PPB;
    int eL[4], rL[4];
    bool vL[4];
    int i4 = t * 4;   // local ids t*4..t*4+3 (threads 244..255 idle: i4>=976)
#pragma unroll
    for (int q = 0; q < 4; ++q) {
        int li = i4 + q;
        vL[q] = (li < cnt);
        if (vL[q]) {
            eL[q] = idx[base + li] & 15;
            rL[q] = atomicAdd(&bins[eL[q]], 1);
        }
    }
    __syncthreads();
    if (t < L_EXP) {   // 16-lane scan of pad4 counts
        int c = bins[t];
        int p = (c + 3) & ~3;
        int s = p;
#pragma unroll
        for (int d = 1; d < L_EXP; d <<= 1) {
            int u = __shfl_up(s, d, L_EXP);
            if (t >= d) s += u;
        }
        poff[t] = s - p;
    }
    __syncthreads();
#pragma unroll
    for (int q = 0; q < 4; ++q)
        if (vL[q]) spid[poff[eL[q]] + rL[q]] =
            (unsigned short)((eL[q] << 10) | (i4 + q));
    __syncthreads();

    // ---- thread processes slots 4t..4t+3 (same expert by construction) ----
    int s0 = (int)spid[4 * t];
    bool any = (s0 != 0xFFFF);
    int e = any ? (s0 >> 10) : 0;
    int l0 = any ? (s0 & 1023) : 0;
    int pid[4]; bool act[4];
#pragma unroll
    for (int q = 0; q < 4; ++q) {
        int sq = (int)spid[4 * t + q];
        act[q] = (sq != 0xFFFF);
        pid[q] = base + (act[q] ? (sq & 1023) : l0);
    }

    const char* w0p = (const char*)sW0 + e * 16;
    const char* w1p = (const char*)sW1 + e * 16;
    const char* w2p = (const char*)sW2 + e * 16;

    h2 xh[4][4];
#pragma unroll
    for (int q = 0; q < 4; ++q) {
        const float* xp = x + (size_t)pid[q] * IN0;
        float4 a = *reinterpret_cast<const float4*>(xp);
        float4 b = *reinterpret_cast<const float4*>(xp + 3);
        xh[q][0] = pk(a.x, a.y);
        xh[q][1] = pk(a.z, a.w);
        xh[q][2] = pk(b.y, b.z);
        xh[q][3] = pk(b.w, 1.0f);   // 1.0 -> bias slot
    }
    __builtin_amdgcn_sched_barrier(0);

    // ---- Layer 0: 7(+bias) -> 16, pairwise rows, weights shared by 4 pts ----
    h2 h0h[4][8];
#pragma unroll
    for (int op = 0; op < 8; ++op) {
        F4H ua, ub;
        ua.f4 = *reinterpret_cast<const float4*>(w0p + (2 * op) * 256);
        ub.f4 = *reinterpret_cast<const float4*>(w0p + (2 * op + 1) * 256);
#pragma unroll
        for (int q = 0; q < 4; ++q) {
            float a0 = 0.f, a1 = 0.f;
            a0 = fdot2(xh[q][0], ua.h[0], a0); a1 = fdot2(xh[q][0], ub.h[0], a1);
            a0 = fdot2(xh[q][1], ua.h[1], a0); a1 = fdot2(xh[q][1], ub.h[1], a1);
            a0 = fdot2(xh[q][2], ua.h[2], a0); a1 = fdot2(xh[q][2], ub.h[2], a1);
            a0 = fdot2(xh[q][3], ua.h[3], a0); a1 = fdot2(xh[q][3], ub.h[3], a1);
            h0h[q][op] = pk(leaky(a0), leaky(a1));
        }
    }
    __builtin_amdgcn_sched_barrier(0);

    // ---- Layers 1+2 fused; REAL loop over 4 chunks of 8 h1-neurons ----
    float h2a[4][C2];
#pragma unroll
    for (int q = 0; q < 4; ++q)
#pragma unroll
        for (int o = 0; o < C2; ++o)
            h2a[q][o] = __half2float(sB2h[o * 16 + e]);
#pragma unroll 1
    for (int ch = 0; ch < 4; ++ch) {   // h1 neurons ch*8 .. ch*8+7
        float tvf[4][8];
#pragma unroll
        for (int o8 = 0; o8 < 8; ++o8) {
            int o = ch * 8 + o8;
            F4H ua, ub;
            ua.f4 = *reinterpret_cast<const float4*>(w1p + (2 * o) * 256);
            ub.f4 = *reinterpret_cast<const float4*>(w1p + (2 * o + 1) * 256);
            float bias = sB1[o * 16 + e];
#pragma unroll
            for (int q = 0; q < 4; ++q) {
                float a = bias;
                a = fdot2(h0h[q][0], ua.h[0], a);
                a = fdot2(h0h[q][1], ua.h[1], a);
                a = fdot2(h0h[q][2], ua.h[2], a);
                a = fdot2(h0h[q][3], ua.h[3], a);
                a = fdot2(h0h[q][4], ub.h[0], a);
                a = fdot2(h0h[q][5], ub.h[1], a);
                a = fdot2(h0h[q][6], ub.h[2], a);
                a = fdot2(h0h[q][7], ub.h[3], a);
                tvf[q][o8] = leaky(a);
            }
        }
        __builtin_amdgcn_sched_barrier(0);
        h2 tvh[4][4];
#pragma unroll
        for (int q = 0; q < 4; ++q)
#pragma unroll
            for (int p = 0; p < 4; ++p)
                tvh[q][p] = pk(tvf[q][2 * p], tvf[q][2 * p + 1]);
#pragma unroll
        for (int o = 0; o < C2; ++o) {
            F4H u;
            u.f4 = *reinterpret_cast<const float4*>(w2p + (4 * o + ch) * 256);
#pragma unroll
            for (int q = 0; q < 4; ++q) {
                float a = h2a[q][o];
                a = fdot2(tvh[q][0], u.h[0], a);
                a = fdot2(tvh[q][1], u.h[1], a);
                a = fdot2(tvh[q][2], u.h[2], a);
                a = fdot2(tvh[q][3], u.h[3], a);
                h2a[q][o] = a;
            }
        }
        __builtin_amdgcn_sched_barrier(0);  // fence at chunk boundary
    }

    // ---- predicated stores ----
#pragma unroll
    for (int q = 0; q < 4; ++q) {
        if (act[q]) {
            float4* outp = reinterpret_cast<float4*>(out + (size_t)pid[q] * C2);
#pragma unroll
            for (int og = 0; og < 4; ++og) {
                float4 o;
                o.x = leaky(h2a[q][og * 4 + 0]);
                o.y = leaky(h2a[q][og * 4 + 1]);
                o.z = leaky(h2a[q][og * 4 + 2]);
                o.w = leaky(h2a[q][og * 4 + 3]);
                outp[og] = o;
            }
        }
    }
}

extern "C" void kernel_launch(void* const* d_in, const int* in_sizes, int n_in,
                              void* d_out, int out_size, void* d_ws, size_t ws_size,
                              hipStream_t stream) {
    const float* x  = (const float*)d_in[0];
    const int*  idx = (const int*)d_in[1];
    const float* W0 = (const float*)d_in[2];
    const float* b0 = (const float*)d_in[3];
    const float* W1 = (const float*)d_in[4];
    const float* b1 = (const float*)d_in[5];
    const float* W2 = (const float*)d_in[6];
    const float* b2 = (const float*)d_in[7];
    float* out = (float*)d_out;

    int n = in_sizes[1];  // N
    int blocks = (n + PPB - 1) / PPB;
    k_fused<<<blocks, BLK, 0, stream>>>(x, idx, W0, b0, W1, b1, W2, b2, out, n);
}